// Round 5
// baseline (563.955 us; speedup 1.0000x reference)
//
#include <hip/hip_runtime.h>
#include <hip/hip_bf16.h>

#define BB 2
#define TT 1024
#define DD 2048
#define NH 16
#define NKV 4
#define DHD 128
#define DVV 256

#define LAMBDA_INIT 0.35550906759096927f
#define ONE_MINUS_LI 0.6444909324090307f
// QK scale * log2(e), folded into Q at rope time (softmax runs in exp2 domain)
#define QSCALE (0.08838834764831845f * 1.4426950408889634f)

typedef __attribute__((ext_vector_type(8))) short bf16x8;
typedef __attribute__((ext_vector_type(4))) float f32x4;

static __device__ __forceinline__ short f2bf_s(float x) {
    __hip_bfloat16 h = __float2bfloat16(x);
    return __builtin_bit_cast(short, h);
}
static __device__ __forceinline__ float bfu2f(unsigned short u) {
    union { float f; unsigned int u32; } x;
    x.u32 = ((unsigned int)u) << 16;
    return x.f;
}

#define GLOAD_LDS16(g, l)                                                      \
    __builtin_amdgcn_global_load_lds(                                          \
        (const __attribute__((address_space(1))) unsigned int*)(g),            \
        (__attribute__((address_space(3))) unsigned int*)(l), 16, 0, 0)

// ---------------- all f32->bf16 casts in ONE dispatch ----------------
// f4-index segments: x | Wq | Wk | Wv | Wo
__global__ void cast_all(const float* __restrict__ x, const float* __restrict__ wq,
                         const float* __restrict__ wk, const float* __restrict__ wv,
                         const float* __restrict__ wo,
                         __hip_bfloat16* __restrict__ dx, __hip_bfloat16* __restrict__ dwqkv,
                         __hip_bfloat16* __restrict__ dwo) {
    const int i = blockIdx.x * 256 + threadIdx.x;
    const float* src;
    ushort4* dst;
    int s4;
    if (i < 1048576) { src = x; dst = (ushort4*)dx; s4 = i; }
    else if (i < 3145728) { src = wq; dst = (ushort4*)dwqkv; s4 = i - 1048576; }
    else if (i < 3670016) { src = wk; dst = (ushort4*)dwqkv + 2097152; s4 = i - 3145728; }
    else if (i < 4194304) { src = wv; dst = (ushort4*)dwqkv + 2621440; s4 = i - 3670016; }
    else { src = wo; dst = (ushort4*)dwo; s4 = i - 4194304; }
    const float4 v = reinterpret_cast<const float4*>(src)[s4];
    union { ushort4 u; __hip_bfloat16 b[4]; } o;
    o.b[0] = __float2bfloat16(v.x);
    o.b[1] = __float2bfloat16(v.y);
    o.b[2] = __float2bfloat16(v.z);
    o.b[3] = __float2bfloat16(v.w);
    dst[s4] = o.u;
}

// ---------------- NT GEMM, 2-phase double-buffered ----------------
__global__ __launch_bounds__(256) void gemm128_db(const __hip_bfloat16* __restrict__ A,
                                                  const __hip_bfloat16* __restrict__ Bm,
                                                  float* __restrict__ C,
                                                  int M, int N, int sK, int kLen) {
    __shared__ ushort As[2][128 * 32];
    __shared__ ushort Bs[2][128 * 32];
    const int tid = threadIdx.x;
    const int lane = tid & 63, wid = tid >> 6;
    const int lo = lane & 15, hi = lane >> 4;
    const int wr = wid >> 1, wc = wid & 1;
    const int m0 = blockIdx.y * 128, n0 = blockIdx.x * 128;
    const int kOff = blockIdx.z * kLen;

    const ushort* gA = (const ushort*)A;
    const ushort* gB = (const ushort*)Bm;
    C += (size_t)blockIdx.z * M * N;

    const int c0row = tid >> 2;
    const int c0col = (tid & 3) << 3;

    auto STAGE = [&](int buf, int kg) {
#pragma unroll
        for (int q = 0; q < 2; ++q) {
            const int row = q * 64 + c0row;
            const int idx = q * 256 + tid;
            GLOAD_LDS16(gA + (size_t)(m0 + row) * sK + kg + c0col, &As[buf][idx << 3]);
            GLOAD_LDS16(gB + (size_t)(n0 + row) * sK + kg + c0col, &Bs[buf][idx << 3]);
        }
    };

    f32x4 acc[4][4];
#pragma unroll
    for (int mi = 0; mi < 4; ++mi)
#pragma unroll
        for (int ni = 0; ni < 4; ++ni) acc[mi][ni] = (f32x4){0.f, 0.f, 0.f, 0.f};

    STAGE(0, kOff);
    const int nt = kLen >> 5;
    for (int t = 0; t < nt; ++t) {
        __syncthreads();
        if (t + 1 < nt) STAGE((t + 1) & 1, kOff + ((t + 1) << 5));
        const ushort* as = &As[t & 1][0];
        const ushort* bs = &Bs[t & 1][0];
        bf16x8 af[4], bfr[4];
#pragma unroll
        for (int mi = 0; mi < 4; ++mi)
            af[mi] = *reinterpret_cast<const bf16x8*>(&as[(wr * 64 + mi * 16 + lo) * 32 + hi * 8]);
#pragma unroll
        for (int ni = 0; ni < 4; ++ni)
            bfr[ni] = *reinterpret_cast<const bf16x8*>(&bs[(wc * 64 + ni * 16 + lo) * 32 + hi * 8]);
#pragma unroll
        for (int mi = 0; mi < 4; ++mi)
#pragma unroll
            for (int ni = 0; ni < 4; ++ni)
                acc[mi][ni] = __builtin_amdgcn_mfma_f32_16x16x32_bf16(af[mi], bfr[ni], acc[mi][ni], 0, 0, 0);
    }
#pragma unroll
    for (int mi = 0; mi < 4; ++mi)
#pragma unroll
        for (int ni = 0; ni < 4; ++ni)
#pragma unroll
            for (int r = 0; r < 4; ++r)
                C[(size_t)(m0 + wr * 64 + mi * 16 + hi * 4 + r) * N + (n0 + wc * 64 + ni * 16 + lo)] =
                    acc[mi][ni][r];
}

// ---------------- split-K reduce ----------------
__global__ void addf4(const float* __restrict__ p, float* __restrict__ out, int n4) {
    int i = blockIdx.x * blockDim.x + threadIdx.x;
    if (i >= n4) return;
    const float4 a = reinterpret_cast<const float4*>(p)[i];
    const float4 b = reinterpret_cast<const float4*>(p)[i + n4];
    float4 o;
    o.x = a.x + b.x; o.y = a.y + b.y; o.z = a.z + b.z; o.w = a.w + b.w;
    reinterpret_cast<float4*>(out)[i] = o;
}

// ---------------- RoPE for Q and K in ONE dispatch ----------------
__global__ void rope_all(const float* __restrict__ in, const int* __restrict__ pos,
                         __hip_bfloat16* __restrict__ qb, __hip_bfloat16* __restrict__ kb) {
    int idx = blockIdx.x * blockDim.x + threadIdx.x;
    int nheads, hshift, col_base, li;
    float scale;
    __hip_bfloat16* outp;
    if (idx < 4194304) { nheads = 16; hshift = 4; col_base = 0; outp = qb; scale = QSCALE; li = idx; }
    else { nheads = 4; hshift = 2; col_base = 4096; outp = kb; scale = 1.0f; li = idx - 4194304; }

    int d2 = li & 63;
    int rest = li >> 6;
    int e = rest & 1;
    int rest2 = rest >> 1;
    int head = rest2 & (nheads - 1);
    int bt = rest2 >> hshift;
    int t = bt & (TT - 1);
    int b = bt >> 10;

    const float* src = in + (size_t)bt * 6144 + col_base + head * 256 + e * 128 + 2 * d2;
    float x1 = src[0], x2 = src[1];
    float inv = expf(-(float)d2 * (2.0f / 128.0f) * 9.210340371976184f);
    float fr = (float)pos[t] * inv;
    float sn, cs;
    sincosf(fr, &sn, &cs);
    float o1 = (x1 * cs - x2 * sn) * scale;
    float o2 = (x1 * sn + x2 * cs) * scale;
    __hip_bfloat16* dst = outp + ((((size_t)e * BB + b) * nheads + head) * TT + t) * DHD + 2 * d2;
    dst[0] = __float2bfloat16(o1);
    dst[1] = __float2bfloat16(o2);
}

// ---------------- V transpose via LDS tile ----------------
__global__ __launch_bounds__(256) void vtrans(const float* __restrict__ in, __hip_bfloat16* __restrict__ out) {
    __shared__ float tle[64][65];
    const int t0 = blockIdx.x * 64;
    const int z = blockIdx.y;
    const int dv0 = (z & 3) * 64;
    const int kvi = (z >> 2) & 3;
    const int b = z >> 4;
    const int tid = threadIdx.x;
    const int rt = tid >> 6, ct = tid & 63;
#pragma unroll
    for (int p = 0; p < 16; ++p) {
        const int ti = p * 4 + rt;
        tle[ti][ct] = in[(size_t)(b * TT + t0 + ti) * 6144 + 5120 + kvi * 256 + dv0 + ct];
    }
    __syncthreads();
#pragma unroll
    for (int p = 0; p < 16; ++p) {
        const int dv = p * 4 + rt;
        out[((size_t)(b * NKV + kvi) * DVV + dv0 + dv) * TT + t0 + ct] = __float2bfloat16(tle[ct][dv]);
    }
}

// ---------------- lambda scalar ----------------
__global__ void lam_k(const float* __restrict__ lq1, const float* __restrict__ lk1,
                      const float* __restrict__ lq2, const float* __restrict__ lk2,
                      float* __restrict__ lam) {
    int l = threadIdx.x;  // 64
    float s1 = lq1[l] * lk1[l] + lq1[l + 64] * lk1[l + 64];
    float s2 = lq2[l] * lk2[l] + lq2[l + 64] * lk2[l + 64];
#pragma unroll
    for (int mm = 1; mm < 64; mm <<= 1) {
        s1 += __shfl_xor(s1, mm, 64);
        s2 += __shfl_xor(s2, mm, 64);
    }
    if (l == 0) lam[0] = expf(s1) - expf(s2) + LAMBDA_INIT;
}

// ---------------- flash attention v4: uniform-work q-tile PAIRS + shared K/V frags ----
// Block = pair (qth = 15-i, qtl = i): always 17 tile-units of work.
// On the overlap range (kt <= qtl), each K/V fragment ds_read feeds MFMAs for
// BOTH q-subtiles (fragments are lane-only-dependent) -> LDS reads/work halved.
#define QK_TWO(SH, SL)                                                              \
    _Pragma("unroll") for (int n = 0; n < 4; ++n) {                                 \
        const int R = ((n >> 1) << 5) + ((lo >> 2) << 3) + ((n & 1) << 2) + (lo & 3); \
        const int swz = ((R & 3) | ((R >> 1) & 4)) << 4;                            \
        _Pragma("unroll") for (int kk = 0; kk < 4; ++kk) {                          \
            bf16x8 kf = *reinterpret_cast<const bf16x8*>(                           \
                (const char*)Ks + R * 256 + ((kk * 64 + hi * 16) ^ swz));           \
            SH[n] = __builtin_amdgcn_mfma_f32_16x16x32_bf16(kf, qfh[kk], SH[n], 0, 0, 0); \
            SL[n] = __builtin_amdgcn_mfma_f32_16x16x32_bf16(kf, qfl[kk], SL[n], 0, 0, 0); \
        }                                                                           \
    }

#define QK_ONE(SH)                                                                  \
    _Pragma("unroll") for (int n = 0; n < 4; ++n) {                                 \
        const int R = ((n >> 1) << 5) + ((lo >> 2) << 3) + ((n & 1) << 2) + (lo & 3); \
        const int swz = ((R & 3) | ((R >> 1) & 4)) << 4;                            \
        _Pragma("unroll") for (int kk = 0; kk < 4; ++kk) {                          \
            bf16x8 kf = *reinterpret_cast<const bf16x8*>(                           \
                (const char*)Ks + R * 256 + ((kk * 64 + hi * 16) ^ swz));           \
            SH[n] = __builtin_amdgcn_mfma_f32_16x16x32_bf16(kf, qfh[kk], SH[n], 0, 0, 0); \
        }                                                                           \
    }

#define SM_STEP(S, M, LSUM, O, PF, ISDIAG, KB, Q0)                                  \
    {                                                                               \
        if (ISDIAG) {                                                               \
            _Pragma("unroll") for (int n = 0; n < 4; ++n) {                         \
                const int kb0 = (KB) + ((n >> 1) << 5) + ((n & 1) << 2) + hi * 8;   \
                _Pragma("unroll") for (int r = 0; r < 4; ++r)                       \
                    if (kb0 + r > (Q0) + lo) S[n][r] = -3e38f;                      \
            }                                                                       \
        }                                                                           \
        float tm = S[0][0];                                                         \
        _Pragma("unroll") for (int n = 0; n < 4; ++n)                               \
            _Pragma("unroll") for (int r = 0; r < 4; ++r) tm = fmaxf(tm, S[n][r]);  \
        tm = fmaxf(tm, __shfl_xor(tm, 16, 64));                                     \
        tm = fmaxf(tm, __shfl_xor(tm, 32, 64));                                     \
        if (!__all(tm <= M + 11.f)) {                                               \
            const float mn = fmaxf(M, tm);                                          \
            const float rsc = __builtin_amdgcn_exp2f(M - mn);                       \
            M = mn; LSUM *= rsc;                                                    \
            float ro[4];                                                            \
            _Pragma("unroll") for (int r = 0; r < 4; ++r) ro[r] = __shfl(rsc, hi * 4 + r, 64); \
            _Pragma("unroll") for (int nc = 0; nc < 16; ++nc)                       \
                _Pragma("unroll") for (int r = 0; r < 4; ++r) O[nc][r] *= ro[r];    \
        }                                                                           \
        float rsum = 0.f;                                                           \
        _Pragma("unroll") for (int n = 0; n < 4; ++n)                               \
            _Pragma("unroll") for (int r = 0; r < 4; ++r) {                         \
                const float p = __builtin_amdgcn_exp2f(S[n][r] - M);                \
                S[n][r] = p; rsum += p;                                             \
            }                                                                       \
        rsum += __shfl_xor(rsum, 16, 64);                                           \
        rsum += __shfl_xor(rsum, 32, 64);                                           \
        LSUM += rsum;                                                               \
        _Pragma("unroll") for (int n = 0; n < 4; ++n)                               \
            _Pragma("unroll") for (int r = 0; r < 4; ++r)                           \
                PF[n >> 1][(n & 1) * 4 + r] = f2bf_s(S[n][r]);                      \
    }

#define EPILOG(LSUM, O, Q0)                                                         \
    {                                                                               \
        const float invl = 1.0f / LSUM;                                             \
        float io[4];                                                                \
        _Pragma("unroll") for (int r = 0; r < 4; ++r) io[r] = __shfl(invl, hi * 4 + r, 64); \
        _Pragma("unroll") for (int nc = 0; nc < 16; ++nc)                           \
            _Pragma("unroll") for (int r = 0; r < 4; ++r)                           \
                op[(size_t)((Q0) + hi * 4 + r) * DVV + nc * 16 + lo] =              \
                    (ushort)f2bf_s(O[nc][r] * io[r]);                               \
    }

__global__ __launch_bounds__(256, 2) void attn_fused(const __hip_bfloat16* __restrict__ qb,
                                                     const __hip_bfloat16* __restrict__ kb,
                                                     const __hip_bfloat16* __restrict__ vtb,
                                                     __hip_bfloat16* __restrict__ Obuf) {
    const int tid = threadIdx.x;
    const int wid = tid >> 6;
    const int lane = tid & 63;
    const int lo = lane & 15, hi = lane >> 4;
    const int pi = blockIdx.x;            // 0..7
    const int qth = 15 - pi, qtl = pi;    // paired q-tiles: (qth+1)+(qtl+1) = 17 units
    const int bh = blockIdx.y;
    const int e = blockIdx.z;
    const int b = bh >> 4, h = bh & 15;
    const int kv = h >> 2;

    const ushort* qp = (const ushort*)qb + (((size_t)e * BB + b) * NH + h) * (size_t)TT * DHD;
    const ushort* kp = (const ushort*)kb + (((size_t)e * BB + b) * NKV + kv) * (size_t)TT * DHD;
    const ushort* vp = (const ushort*)vtb + ((size_t)b * NKV + kv) * (size_t)DVV * TT;

    const int q0h = qth * 64 + wid * 16;
    const int q0l = qtl * 64 + wid * 16;

    __shared__ ushort Ks[64 * 128];   // 16 KB
    __shared__ ushort Vs[256 * 64];   // 32 KB

    bf16x8 qfh[4], qfl[4];
#pragma unroll
    for (int kk = 0; kk < 4; ++kk) {
        qfh[kk] = *reinterpret_cast<const bf16x8*>(qp + (size_t)(q0h + lo) * DHD + kk * 32 + hi * 8);
        qfl[kk] = *reinterpret_cast<const bf16x8*>(qp + (size_t)(q0l + lo) * DHD + kk * 32 + hi * 8);
    }

    f32x4 Oh[16], Ol[16];
#pragma unroll
    for (int nc = 0; nc < 16; ++nc) {
        Oh[nc] = (f32x4){0.f, 0.f, 0.f, 0.f};
        Ol[nc] = (f32x4){0.f, 0.f, 0.f, 0.f};
    }
    float mh = -3e38f, sumh = 0.f;
    float ml = -3e38f, suml = 0.f;

    for (int kt = 0; kt <= qth; ++kt) {
        const int kbase = kt * 64;
        // ---- stage K (64x128) + V^T (256x64), swizzled via pre-swizzled source ----
#pragma unroll
        for (int p2 = 0; p2 < 4; ++p2) {
            const int idx = p2 * 256 + tid;
            const int row = idx >> 4, c = idx & 15;
            const int cp = c ^ ((row & 3) | ((row >> 1) & 4));
            GLOAD_LDS16(kp + (((size_t)(kbase + row)) << 7) + (cp << 3), &Ks[idx << 3]);
        }
#pragma unroll
        for (int p2 = 0; p2 < 8; ++p2) {
            const int idx = p2 * 256 + tid;
            const int dv = idx >> 3, c = idx & 7;
            const int cp = c ^ (dv & 7);
            GLOAD_LDS16(vp + (size_t)dv * TT + kbase + (cp << 3), &Vs[idx << 3]);
        }
        __syncthreads();

        const bool dol = (kt <= qtl);
        f32x4 sh[4], sl[4];
#pragma unroll
        for (int n = 0; n < 4; ++n) {
            sh[n] = (f32x4){0.f, 0.f, 0.f, 0.f};
            sl[n] = (f32x4){0.f, 0.f, 0.f, 0.f};
        }
        __builtin_amdgcn_s_setprio(1);
        if (dol) { QK_TWO(sh, sl); }
        else { QK_ONE(sh); }
        __builtin_amdgcn_s_setprio(0);

        bf16x8 pfh[2], pfl[2];
        SM_STEP(sh, mh, sumh, Oh, pfh, kt == qth, kbase, q0h);
        if (dol) SM_STEP(sl, ml, suml, Ol, pfl, kt == qtl, kbase, q0l);

        __builtin_amdgcn_s_setprio(1);
        if (dol) {
#pragma unroll
            for (int nc = 0; nc < 16; ++nc) {
                const int vrow = (nc * 16 + lo) * 128;
                const int vswz = (lo & 7) << 4;
#pragma unroll
                for (int ks = 0; ks < 2; ++ks) {
                    bf16x8 vf = *reinterpret_cast<const bf16x8*>(
                        (const char*)Vs + vrow + ((ks * 64 + hi * 16) ^ vswz));
                    Oh[nc] = __builtin_amdgcn_mfma_f32_16x16x32_bf16(pfh[ks], vf, Oh[nc], 0, 0, 0);
                    Ol[nc] = __builtin_amdgcn_mfma_f32_16x16x32_bf16(pfl[ks], vf, Ol[nc], 0, 0, 0);
                }
            }
        } else {
#pragma unroll
            for (int nc = 0; nc < 16; ++nc) {
                const int vrow = (nc * 16 + lo) * 128;
                const int vswz = (lo & 7) << 4;
#pragma unroll
                for (int ks = 0; ks < 2; ++ks) {
                    bf16x8 vf = *reinterpret_cast<const bf16x8*>(
                        (const char*)Vs + vrow + ((ks * 64 + hi * 16) ^ vswz));
                    Oh[nc] = __builtin_amdgcn_mfma_f32_16x16x32_bf16(pfh[ks], vf, Oh[nc], 0, 0, 0);
                }
            }
        }
        __builtin_amdgcn_s_setprio(0);
        __syncthreads();
    }
    ushort* op = (ushort*)Obuf + (((size_t)e * BB + b) * NH + h) * (size_t)TT * DVV;
    EPILOG(sumh, Oh, q0h);
    EPILOG(suml, Ol, q0l);
}

// ---------------- combine + GroupNorm, one wave per (b,h,t) row ----------------
__global__ __launch_bounds__(256) void gn_combine(const __hip_bfloat16* __restrict__ Obuf,
                                                  const float* __restrict__ lamp,
                                                  const float* __restrict__ gw, const float* __restrict__ gb,
                                                  __hip_bfloat16* __restrict__ obf) {
    const int wid = threadIdx.x >> 6, lane = threadIdx.x & 63;
    const int rid = blockIdx.x * 4 + wid;  // (b*NH + h)*TT + t
    const int t = rid & (TT - 1);
    const int h = (rid >> 10) & 15;
    const int b = rid >> 14;
    const float lam = lamp[0];
    const size_t E = (size_t)BB * NH * TT * DVV;
    const ushort* o1p = (const ushort*)Obuf + (size_t)rid * DVV + lane * 4;
    const ushort4 u1 = *reinterpret_cast<const ushort4*>(o1p);
    const ushort4 u2 = *reinterpret_cast<const ushort4*>(o1p + E);
    float val[4];
    val[0] = bfu2f(u1.x) - lam * bfu2f(u2.x);
    val[1] = bfu2f(u1.y) - lam * bfu2f(u2.y);
    val[2] = bfu2f(u1.z) - lam * bfu2f(u2.z);
    val[3] = bfu2f(u1.w) - lam * bfu2f(u2.w);
    float sum = val[0] + val[1] + val[2] + val[3];
    float ss = val[0] * val[0] + val[1] * val[1] + val[2] * val[2] + val[3] * val[3];
#pragma unroll
    for (int mm = 1; mm < 64; mm <<= 1) {
        sum += __shfl_xor(sum, mm, 64);
        ss += __shfl_xor(ss, mm, 64);
    }
    const float mean = sum * (1.0f / 256.0f);
    const float var = ss * (1.0f / 256.0f) - mean * mean;
    const float rs = rsqrtf(var + 1e-5f);
    const int c = h * 256 + lane * 4;
    const float4 gwv = *reinterpret_cast<const float4*>(gw + c);
    const float4 gbv = *reinterpret_cast<const float4*>(gb + c);
    union { ushort4 u; short s[4]; } o;
    o.s[0] = f2bf_s(((val[0] - mean) * rs * gwv.x + gbv.x) * ONE_MINUS_LI);
    o.s[1] = f2bf_s(((val[1] - mean) * rs * gwv.y + gbv.y) * ONE_MINUS_LI);
    o.s[2] = f2bf_s(((val[2] - mean) * rs * gwv.z + gbv.z) * ONE_MINUS_LI);
    o.s[3] = f2bf_s(((val[3] - mean) * rs * gwv.w + gbv.w) * ONE_MINUS_LI);
    const int bt = b * TT + t;
    *reinterpret_cast<ushort4*>((ushort*)obf + (size_t)bt * 4096 + c) = o.u;
}

// ---------------- launch ----------------
extern "C" void kernel_launch(void* const* d_in, const int* in_sizes, int n_in,
                              void* d_out, int out_size, void* d_ws, size_t ws_size,
                              hipStream_t stream) {
    const float* x = (const float*)d_in[0];
    const float* Wq = (const float*)d_in[1];
    const float* Wk = (const float*)d_in[2];
    const float* Wv = (const float*)d_in[3];
    const float* Wo = (const float*)d_in[4];
    const float* lq1 = (const float*)d_in[5];
    const float* lk1 = (const float*)d_in[6];
    const float* lq2 = (const float*)d_in[7];
    const float* lk2 = (const float*)d_in[8];
    const float* gw = (const float*)d_in[9];
    const float* gb = (const float*)d_in[10];
    const int* pos = (const int*)d_in[11];

    char* ws = (char*)d_ws;
    const size_t oXB = 0;                   // x bf16               8,388,608
    const size_t oWQKV = 8388608;           // [Wq;Wk;Wv] bf16     25,165,824
    const size_t oWO = 33554432;            // Wo bf16             16,777,216
    const size_t oQKVF = 50331648;          // QKV f32 [2048][6144] 50,331,648
    const size_t oOB = 50331648;            // attn out bf16 (alias, 33,554,432)
    const size_t oPK = 50331648;            // split-K partials f32 (alias, 33,554,432)
    const size_t oLAM = 83886080;           // lambda f32 (in dead QKVF tail; after vtrans)
    const size_t oQB = 100663296;           // q rope bf16         16,777,216
    const size_t oKB = 117440512;           // k rope bf16          4,194,304
    const size_t oVT = 121634816;           // v^T bf16             4,194,304
    const size_t oON = 125829120;           // post-GN bf16        16,777,216  (end 142,606,336)

    auto bfp = [&](size_t off) { return (__hip_bfloat16*)(ws + off); };
    auto fp = [&](size_t off) { return (float*)(ws + off); };

    // all input casts (x, Wq, Wk, Wv, Wo) in one dispatch
    cast_all<<<dim3(24576), 256, 0, stream>>>(x, Wq, Wk, Wv, Wo, bfp(oXB), bfp(oWQKV), bfp(oWO));

    // fused QKV projection: [2048][2048] x [6144][2048]^T -> [2048][6144]
    gemm128_db<<<dim3(6144 / 128, 2048 / 128, 1), 256, 0, stream>>>(
        bfp(oXB), bfp(oWQKV), fp(oQKVF), 2048, 6144, 2048, 2048);

    // rope Q+K in one dispatch (Q gets QK_SCALE*log2e folded in)
    rope_all<<<dim3(20480), 256, 0, stream>>>(fp(oQKVF), pos, bfp(oQB), bfp(oKB));
    vtrans<<<dim3(TT / 64, BB * NKV * 4), 256, 0, stream>>>(fp(oQKVF), bfp(oVT));

    lam_k<<<dim3(1), 64, 0, stream>>>(lq1, lk1, lq2, lk2, fp(oLAM));

    // attention (uniform-work q-tile pairs; both variants via z)
    attn_fused<<<dim3(8, BB * NH, 2), 256, 0, stream>>>(bfp(oQB), bfp(oKB), bfp(oVT), bfp(oOB));

    // combine + groupnorm
    gn_combine<<<dim3(BB * NH * TT / 4), 256, 0, stream>>>(bfp(oOB), fp(oLAM), gw, gb, bfp(oON));

    // output projection, split-K x2, then reduce
    gemm128_db<<<dim3(2048 / 128, 2048 / 128, 2), 256, 0, stream>>>(
        bfp(oON), bfp(oWO), fp(oPK), 2048, 2048, 4096, 2048);
    int n = 2048 * 2048 / 4;
    addf4<<<dim3((n + 255) / 256), 256, 0, stream>>>(fp(oPK), (float*)d_out, n);
}